// Round 7
// baseline (90.702 us; speedup 1.0000x reference)
//
#include <hip/hip_runtime.h>

#define BATCH 8192
#define HIDDEN 8192
#define NUM_SEEDS 16
#define CHUNK 512                 // HIDDEN / NUM_SEEDS
#define H4 (HIDDEN / 4)           // 2048 float4s per row
#define N4 ((long long)BATCH * HIDDEN / 4)   // 16,777,216 float4s total

#define GRID 2048
#define BLOCK 256

typedef float f32x4 __attribute__((ext_vector_type(4)));

__global__ __launch_bounds__(BLOCK) void seed_layer_kernel(
    const f32x4* __restrict__ x4,
    const int*   __restrict__ lifecycle,
    const int*   __restrict__ blueprint,
    const int*   __restrict__ strategy,
    const f32x4* __restrict__ weights4,
    f32x4*       __restrict__ out4,
    long long quarter)                   // N4/4, runtime arg -> dynamic loop
{
    const int tid = blockIdx.x * BLOCK + threadIdx.x;   // 0 .. 524287

    // Grid-stride step (= 524288) and `quarter` (= 4194304) are both
    // multiples of H4, so h4/sid/coeffs/w are loop-invariant AND shared by
    // all four streams.
    const int h4  = tid & (H4 - 1);          // float4 index within a row
    const int sid = h4 >> 7;                 // (h4*4) / CHUNK

    const int life = lifecycle[sid];
    const int strt = strategy[sid];
    const int bp   = blueprint[sid];
    const bool active = (life >= 3) && (life <= 6);

    // out = cx*x + cw*w + cm*(x*w)  ==  (cx + cm*w)*x + cw*w  ==  a*x + b
    float cx, cw, cm;
    if (!active)         { cx = 1.0f; cw = 0.0f; cm = 0.0f; }   // identity
    else if (strt == 0)  { cx = 0.0f; cw = 0.0f; cm = 1.0f; }   // x*w
    else if (strt == 1)  { cx = 1.0f; cw = 1.0f; cm = 0.0f; }   // x+w
    else                 { cx = 0.5f; cw = 0.5f; cm = 0.0f; }   // 0.5x+0.5w

    const f32x4 wv = weights4[bp * H4 + h4];             // one gather, cached
    f32x4 a, b;
    a.x = fmaf(cm, wv.x, cx); a.y = fmaf(cm, wv.y, cx);
    a.z = fmaf(cm, wv.z, cx); a.w = fmaf(cm, wv.w, cx);
    b.x = cw * wv.x; b.y = cw * wv.y; b.z = cw * wv.z; b.w = cw * wv.w;

    const long long stride = (long long)GRID * BLOCK;

    // Dynamic-bound loop (R5-proven shape) + NT stores (R6-proven, +25%).
    // Four independent far-apart streams per iteration double the in-flight
    // loads vs R6 — A/B isolates latency- vs BW-limited.
    for (long long i = tid; i < quarter; i += stride) {
        const f32x4 xv0 = x4[i];
        const f32x4 xv1 = x4[i + quarter];
        const f32x4 xv2 = x4[i + 2 * quarter];
        const f32x4 xv3 = x4[i + 3 * quarter];
        f32x4 o0, o1, o2, o3;
        o0.x = fmaf(a.x, xv0.x, b.x); o0.y = fmaf(a.y, xv0.y, b.y);
        o0.z = fmaf(a.z, xv0.z, b.z); o0.w = fmaf(a.w, xv0.w, b.w);
        o1.x = fmaf(a.x, xv1.x, b.x); o1.y = fmaf(a.y, xv1.y, b.y);
        o1.z = fmaf(a.z, xv1.z, b.z); o1.w = fmaf(a.w, xv1.w, b.w);
        o2.x = fmaf(a.x, xv2.x, b.x); o2.y = fmaf(a.y, xv2.y, b.y);
        o2.z = fmaf(a.z, xv2.z, b.z); o2.w = fmaf(a.w, xv2.w, b.w);
        o3.x = fmaf(a.x, xv3.x, b.x); o3.y = fmaf(a.y, xv3.y, b.y);
        o3.z = fmaf(a.z, xv3.z, b.z); o3.w = fmaf(a.w, xv3.w, b.w);
        __builtin_nontemporal_store(o0, out4 + i);
        __builtin_nontemporal_store(o1, out4 + i + quarter);
        __builtin_nontemporal_store(o2, out4 + i + 2 * quarter);
        __builtin_nontemporal_store(o3, out4 + i + 3 * quarter);
    }
}

extern "C" void kernel_launch(void* const* d_in, const int* in_sizes, int n_in,
                              void* d_out, int out_size, void* d_ws, size_t ws_size,
                              hipStream_t stream) {
    const f32x4* x4        = (const f32x4*)d_in[0];
    const int*   lifecycle = (const int*)d_in[1];
    const int*   blueprint = (const int*)d_in[2];
    const int*   strategy  = (const int*)d_in[3];
    const f32x4* weights4  = (const f32x4*)d_in[4];
    // d_in[5] is chunk_size scalar (512) — compile-time constant here.

    f32x4* out4 = (f32x4*)d_out;
    const long long quarter = N4 / 4;   // 4,194,304

    seed_layer_kernel<<<GRID, BLOCK, 0, stream>>>(
        x4, lifecycle, blueprint, strategy, weights4, out4, quarter);
}

// Round 8
// 89.557 us; speedup vs baseline: 1.0128x; 1.0128x over previous
//
#include <hip/hip_runtime.h>

#define BATCH 8192
#define HIDDEN 8192
#define NUM_SEEDS 16
#define CHUNK 512                 // HIDDEN / NUM_SEEDS
#define H4 (HIDDEN / 4)           // 2048 float4s per row
#define N4 ((long long)BATCH * HIDDEN / 4)   // 16,777,216 float4s total

#define GRID 2048
#define BLOCK 256

typedef float f32x4 __attribute__((ext_vector_type(4)));

__global__ __launch_bounds__(BLOCK) void seed_layer_kernel(
    const f32x4* __restrict__ x4,
    const int*   __restrict__ lifecycle,
    const int*   __restrict__ blueprint,
    const int*   __restrict__ strategy,
    const f32x4* __restrict__ weights4,
    f32x4*       __restrict__ out4,
    long long half)                      // N4/2, runtime arg -> dynamic loop
{
    const int tid = blockIdx.x * BLOCK + threadIdx.x;   // 0 .. 524287

    // Grid-stride step (= 524288) and `half` (= 8388608) are both multiples
    // of H4, so h4/sid/coeffs/w are loop-invariant AND shared by both streams.
    const int h4  = tid & (H4 - 1);          // float4 index within a row
    const int sid = h4 >> 7;                 // (h4*4) / CHUNK

    const int life = lifecycle[sid];
    const int strt = strategy[sid];
    const int bp   = blueprint[sid];
    const bool active = (life >= 3) && (life <= 6);

    // out = cx*x + cw*w + cm*(x*w)  ==  (cx + cm*w)*x + cw*w  ==  a*x + b
    float cx, cw, cm;
    if (!active)         { cx = 1.0f; cw = 0.0f; cm = 0.0f; }   // identity
    else if (strt == 0)  { cx = 0.0f; cw = 0.0f; cm = 1.0f; }   // x*w
    else if (strt == 1)  { cx = 1.0f; cw = 1.0f; cm = 0.0f; }   // x+w
    else                 { cx = 0.5f; cw = 0.5f; cm = 0.0f; }   // 0.5x+0.5w

    const f32x4 wv = weights4[bp * H4 + h4];             // one gather, cached
    f32x4 a, b;
    a.x = fmaf(cm, wv.x, cx); a.y = fmaf(cm, wv.y, cx);
    a.z = fmaf(cm, wv.z, cx); a.w = fmaf(cm, wv.w, cx);
    b.x = cw * wv.x; b.y = cw * wv.y; b.z = cw * wv.z; b.w = cw * wv.w;

    const long long stride = (long long)GRID * BLOCK;

    // Cache partitioning: i = tid + it*2^19, so bit16 of every address a
    // thread touches equals bit16 of its tid — a per-thread-constant
    // predicate selecting interleaved 1-MiB granules. Threads with bit16=1
    // NT-load their region-B element (64 MiB always-miss slice); everything
    // else stays on the cached path. Cached working set = 128 + 64 = 192 MiB
    // < 256 MiB L3 -> should stay fully resident across replays.
    const bool ntB = (tid >> 16) & 1;

    if (ntB) {
        for (long long i = tid; i < half; i += stride) {
            const f32x4 xv0 = x4[i];
            const f32x4 xv1 = __builtin_nontemporal_load(x4 + i + half);
            f32x4 o0, o1;
            o0.x = fmaf(a.x, xv0.x, b.x); o0.y = fmaf(a.y, xv0.y, b.y);
            o0.z = fmaf(a.z, xv0.z, b.z); o0.w = fmaf(a.w, xv0.w, b.w);
            o1.x = fmaf(a.x, xv1.x, b.x); o1.y = fmaf(a.y, xv1.y, b.y);
            o1.z = fmaf(a.z, xv1.z, b.z); o1.w = fmaf(a.w, xv1.w, b.w);
            __builtin_nontemporal_store(o0, out4 + i);
            __builtin_nontemporal_store(o1, out4 + i + half);
        }
    } else {
        for (long long i = tid; i < half; i += stride) {
            const f32x4 xv0 = x4[i];
            const f32x4 xv1 = x4[i + half];
            f32x4 o0, o1;
            o0.x = fmaf(a.x, xv0.x, b.x); o0.y = fmaf(a.y, xv0.y, b.y);
            o0.z = fmaf(a.z, xv0.z, b.z); o0.w = fmaf(a.w, xv0.w, b.w);
            o1.x = fmaf(a.x, xv1.x, b.x); o1.y = fmaf(a.y, xv1.y, b.y);
            o1.z = fmaf(a.z, xv1.z, b.z); o1.w = fmaf(a.w, xv1.w, b.w);
            __builtin_nontemporal_store(o0, out4 + i);
            __builtin_nontemporal_store(o1, out4 + i + half);
        }
    }
}

extern "C" void kernel_launch(void* const* d_in, const int* in_sizes, int n_in,
                              void* d_out, int out_size, void* d_ws, size_t ws_size,
                              hipStream_t stream) {
    const f32x4* x4        = (const f32x4*)d_in[0];
    const int*   lifecycle = (const int*)d_in[1];
    const int*   blueprint = (const int*)d_in[2];
    const int*   strategy  = (const int*)d_in[3];
    const f32x4* weights4  = (const f32x4*)d_in[4];
    // d_in[5] is chunk_size scalar (512) — compile-time constant here.

    f32x4* out4 = (f32x4*)d_out;
    const long long half = N4 / 2;   // 8,388,608

    seed_layer_kernel<<<GRID, BLOCK, 0, stream>>>(
        x4, lifecycle, blueprint, strategy, weights4, out4, half);
}

// Round 9
// 86.459 us; speedup vs baseline: 1.0491x; 1.0358x over previous
//
#include <hip/hip_runtime.h>

#define BATCH 8192
#define HIDDEN 8192
#define NUM_SEEDS 16
#define CHUNK 512                 // HIDDEN / NUM_SEEDS
#define H4 (HIDDEN / 4)           // 2048 float4s per row
#define N4 ((long long)BATCH * HIDDEN / 4)   // 16,777,216 float4s total

#define GRID 2048
#define BLOCK 256

typedef float f32x4 __attribute__((ext_vector_type(4)));

// R6 champion configuration — 85.36 us = 537 MB CU-side / 6.29 TB/s, i.e.
// the measured mixed-stream fabric ceiling. Proven levers:
//   * dynamic-bound grid-stride loop (static unroll regressed: R4)
//   * 2 far-apart streams/thread sharing loop-invariant a,b (4 regressed: R7)
//   * cached loads (NT-load regressed: R3/R8), NT stores (+25%: R6)
__global__ __launch_bounds__(BLOCK) void seed_layer_kernel(
    const f32x4* __restrict__ x4,
    const int*   __restrict__ lifecycle,
    const int*   __restrict__ blueprint,
    const int*   __restrict__ strategy,
    const f32x4* __restrict__ weights4,
    f32x4*       __restrict__ out4,
    long long half)                      // N4/2, runtime arg -> dynamic loop
{
    const int tid = blockIdx.x * BLOCK + threadIdx.x;   // 0 .. 524287

    // Grid-stride step (= 524288) and `half` (= 8388608) are both multiples
    // of H4, so h4/sid/coeffs/w are loop-invariant AND shared by both streams.
    const int h4  = tid & (H4 - 1);          // float4 index within a row
    const int sid = h4 >> 7;                 // (h4*4) / CHUNK

    const int life = lifecycle[sid];
    const int strt = strategy[sid];
    const int bp   = blueprint[sid];
    const bool active = (life >= 3) && (life <= 6);

    // out = cx*x + cw*w + cm*(x*w)  ==  (cx + cm*w)*x + cw*w  ==  a*x + b
    float cx, cw, cm;
    if (!active)         { cx = 1.0f; cw = 0.0f; cm = 0.0f; }   // identity
    else if (strt == 0)  { cx = 0.0f; cw = 0.0f; cm = 1.0f; }   // x*w
    else if (strt == 1)  { cx = 1.0f; cw = 1.0f; cm = 0.0f; }   // x+w
    else                 { cx = 0.5f; cw = 0.5f; cm = 0.0f; }   // 0.5x+0.5w

    const f32x4 wv = weights4[bp * H4 + h4];             // one gather, cached
    f32x4 a, b;
    a.x = fmaf(cm, wv.x, cx); a.y = fmaf(cm, wv.y, cx);
    a.z = fmaf(cm, wv.z, cx); a.w = fmaf(cm, wv.w, cx);
    b.x = cw * wv.x; b.y = cw * wv.y; b.z = cw * wv.z; b.w = cw * wv.w;

    const long long stride = (long long)GRID * BLOCK;

    for (long long i = tid; i < half; i += stride) {
        const f32x4 xv0 = x4[i];
        const f32x4 xv1 = x4[i + half];
        f32x4 o0, o1;
        o0.x = fmaf(a.x, xv0.x, b.x);
        o0.y = fmaf(a.y, xv0.y, b.y);
        o0.z = fmaf(a.z, xv0.z, b.z);
        o0.w = fmaf(a.w, xv0.w, b.w);
        o1.x = fmaf(a.x, xv1.x, b.x);
        o1.y = fmaf(a.y, xv1.y, b.y);
        o1.z = fmaf(a.z, xv1.z, b.z);
        o1.w = fmaf(a.w, xv1.w, b.w);
        __builtin_nontemporal_store(o0, out4 + i);
        __builtin_nontemporal_store(o1, out4 + i + half);
    }
}

extern "C" void kernel_launch(void* const* d_in, const int* in_sizes, int n_in,
                              void* d_out, int out_size, void* d_ws, size_t ws_size,
                              hipStream_t stream) {
    const f32x4* x4        = (const f32x4*)d_in[0];
    const int*   lifecycle = (const int*)d_in[1];
    const int*   blueprint = (const int*)d_in[2];
    const int*   strategy  = (const int*)d_in[3];
    const f32x4* weights4  = (const f32x4*)d_in[4];
    // d_in[5] is chunk_size scalar (512) — compile-time constant here.

    f32x4* out4 = (f32x4*)d_out;
    const long long half = N4 / 2;   // 8,388,608

    seed_layer_kernel<<<GRID, BLOCK, 0, stream>>>(
        x4, lifecycle, blueprint, strategy, weights4, out4, half);
}